// Round 5
// baseline (97.493 us; speedup 1.0000x reference)
//
#include <hip/hip_runtime.h>
#include <math.h>

#define DIM 1024
#define D4  (DIM / 4)      // 256 float4 per row
#define SNUM 5
#define EPSL 1e-6f
#define MARGINL 1.0f
#define NBUCKET 64
#define FIXSCALE 4294967296.0  // 2^32

__device__ __forceinline__ float sq4(const float4& x, const float4& y) {
    float dx = x.x - y.x + EPSL;
    float dy = x.y - y.y + EPSL;
    float dz = x.z - y.z + EPSL;
    float dw = x.w - y.w + EPSL;
    return dx * dx + dy * dy + dz * dz + dw * dw;
}

// One block (256 threads) per anchor k; thread t owns float4 slot t of each row.
// All 12 row-loads issued up front (independent -> max memory-level parallelism;
// R3/R4's wave-per-anchor had 4x fewer waves and serialized slice rounds ->
// latency-bound at 43us). Mean is fused: per-block fixed-point atomicAdd into 64
// buckets + last-block-finishes reduction (integer adds -> deterministic).
__global__ __launch_bounds__(256, 2) void hinge_kernel(const float* __restrict__ vfeat,
                                                       const float* __restrict__ afeat,
                                                       unsigned long long* __restrict__ bucket,
                                                       unsigned int* __restrict__ done_ctr,
                                                       float* __restrict__ out,
                                                       int B, int nblocks) {
    // XCD-chunked bijective swizzle: each XCD owns a contiguous anchor range so
    // neighbor rows k+1..k+5 are re-read from its own L2 (R2: -46%).
    int b = blockIdx.x;
    if ((nblocks & 7) == 0) {
        const int chunk = nblocks >> 3;
        b = (b & 7) * chunk + (b >> 3);
    }
    const int k = b;
    const int t = threadIdx.x;
    const int wave = t >> 6;
    const int lane = t & 63;

    // uniform negative indices
    int j[SNUM];
    #pragma unroll
    for (int m = 0; m < SNUM; ++m) {
        int tt = k + m + 1;
        if (m == k) tt = k + 1;          // reference's m==k case (only k<SNUM)
        if (tt >= B) tt -= B;
        j[m] = tt;
    }

    const float4* __restrict__ v4 = reinterpret_cast<const float4*>(vfeat);
    const float4* __restrict__ a4 = reinterpret_cast<const float4*>(afeat);

    // issue all 12 independent loads before any use
    const float4 vk = v4[(size_t)k * D4 + t];
    const float4 ak = a4[(size_t)k * D4 + t];
    float4 aj[SNUM], vj[SNUM];
    #pragma unroll
    for (int m = 0; m < SNUM; ++m) {
        aj[m] = a4[(size_t)j[m] * D4 + t];
        vj[m] = v4[(size_t)j[m] * D4 + t];
    }

    float acc[11];
    acc[0] = sq4(vk, ak);
    #pragma unroll
    for (int m = 0; m < SNUM; ++m) {
        acc[1 + m]        = sq4(vk, aj[m]);
        acc[1 + SNUM + m] = sq4(ak, vj[m]);
    }

    // 64-lane butterfly reduction of the 11 partials
    #pragma unroll
    for (int off = 32; off > 0; off >>= 1) {
        #pragma unroll
        for (int i = 0; i < 11; ++i)
            acc[i] += __shfl_xor(acc[i], off, 64);
    }

    __shared__ float sh[4][11];
    __shared__ int sh_last;
    if (lane == 0) {
        #pragma unroll
        for (int i = 0; i < 11; ++i) sh[wave][i] = acc[i];
    }
    __syncthreads();

    if (t == 0) {
        float tot[11];
        #pragma unroll
        for (int i = 0; i < 11; ++i)
            tot[i] = sh[0][i] + sh[1][i] + sh[2][i] + sh[3][i];

        const float d_p = sqrtf(tot[0]);
        float dn1 = sqrtf(tot[1]);
        float dn2 = sqrtf(tot[1 + SNUM]);
        #pragma unroll
        for (int m = 1; m < SNUM; ++m) {
            dn1 = fminf(dn1, sqrtf(tot[1 + m]));
            dn2 = fminf(dn2, sqrtf(tot[1 + SNUM + m]));
        }
        const float h = fmaxf(MARGINL + 2.0f * d_p - dn1 - dn2, 0.0f);

        // deterministic fixed-point accumulate, 64-way bucketed to avoid
        // single-address contention
        unsigned long long fx = (unsigned long long)((double)h * FIXSCALE + 0.5);
        atomicAdd(&bucket[blockIdx.x & (NBUCKET - 1)], fx);
        __threadfence();
        unsigned int old = atomicAdd(done_ctr, 1u);
        sh_last = (old == (unsigned int)(nblocks - 1)) ? 1 : 0;
    }
    __syncthreads();

    // last block: wave 0 reads all 64 buckets in parallel, butterfly-sums
    if (sh_last && wave == 0) {
        unsigned long long vsum = atomicAdd(&bucket[lane], 0ull);  // coherent read
        #pragma unroll
        for (int off = 32; off > 0; off >>= 1)
            vsum += __shfl_xor(vsum, off, 64);
        if (lane == 0)
            out[0] = (float)(((double)vsum / FIXSCALE) / (double)B);
    }
}

extern "C" void kernel_launch(void* const* d_in, const int* in_sizes, int n_in,
                              void* d_out, int out_size, void* d_ws, size_t ws_size,
                              hipStream_t stream) {
    const float* vfeat = (const float*)d_in[0];
    const float* afeat = (const float*)d_in[1];
    const int B = in_sizes[0] / DIM;
    const int nblocks = B;

    unsigned long long* bucket = (unsigned long long*)d_ws;          // 64 * 8 B
    unsigned int* done_ctr = (unsigned int*)((char*)d_ws + NBUCKET * 8);
    float* out = (float*)d_out;

    // zero buckets + counter each call (graph-capturable memset node)
    hipMemsetAsync(d_ws, 0, NBUCKET * 8 + 16, stream);

    hinge_kernel<<<nblocks, 256, 0, stream>>>(vfeat, afeat, bucket, done_ctr, out,
                                              B, nblocks);
}

// Round 7
// 24.241 us; speedup vs baseline: 4.0218x; 4.0218x over previous
//
#include <hip/hip_runtime.h>
#include <math.h>

#define DIM 1024
#define D4  (DIM / 4)      // 256 float4 per row
#define SNUM 5
#define EPSL 1e-6f
#define MARGINL 1.0f

__device__ __forceinline__ float sq4(const float4& x, const float4& y) {
    float dx = x.x - y.x + EPSL;
    float dy = x.y - y.y + EPSL;
    float dz = x.z - y.z + EPSL;
    float dw = x.w - y.w + EPSL;
    return dx * dx + dy * dy + dz * dz + dw * dw;
}

// One block (256 threads) per anchor PAIR (k0=2b, k1=2b+1); thread t owns float4
// slot t of each row. Anchors k0,k1 share neighbor rows k0+2..k0+5, and k1's own
// row IS k0's first negative -> 14 row-loads per pair instead of 24.
// R6 bug fixed: waves reduce only their 64-lane quarter of the row, so the 22
// partials MUST be combined across waves in LDS BEFORE the nonlinear
// sqrt/min/hinge tail.
__global__ __launch_bounds__(256) void hinge_kernel(const float* __restrict__ vfeat,
                                                    const float* __restrict__ afeat,
                                                    float* __restrict__ bsum,
                                                    int B, int nblocks) {
    // XCD-chunked bijective swizzle: contiguous anchor range per XCD -> neighbor
    // rows re-read from the local L2 (R2: -46%).
    int b = blockIdx.x;
    if ((nblocks & 7) == 0) {
        const int chunk = nblocks >> 3;
        b = (b & 7) * chunk + (b >> 3);
    }
    const int k0 = 2 * b;
    const int k1 = k0 + 1;
    const int t = threadIdx.x;
    const int wave = t >> 6;
    const int lane = t & 63;

    const float4* __restrict__ v4 = reinterpret_cast<const float4*>(vfeat);
    const float4* __restrict__ a4 = reinterpret_cast<const float4*>(afeat);

    const float4 vk0 = v4[(size_t)k0 * D4 + t];
    const float4 ak0 = a4[(size_t)k0 * D4 + t];
    const float4 vk1 = v4[(size_t)k1 * D4 + t];
    const float4 ak1 = a4[(size_t)k1 * D4 + t];

    // acc layout: [0]=pos0, [1..5]=n1_0, [6..10]=n2_0,
    //             [11]=pos1, [12..16]=n1_1, [17..21]=n2_1
    float acc[22];
    acc[0]  = sq4(vk0, ak0);
    acc[11] = sq4(vk1, ak1);

    if (k0 >= SNUM) {
        // fast path: k0's negatives are rows k0+1..k0+5 (k0+1 == k1, in regs),
        // k1's negatives are rows k0+2..k0+6; rows k0+2..k0+5 feed BOTH anchors.
        acc[1] = sq4(vk0, ak1);
        acc[6] = sq4(ak0, vk1);
        #pragma unroll
        for (int r = 2; r <= 6; ++r) {
            int row = k0 + r;
            if (row >= B) row -= B;
            const float4 arow = a4[(size_t)row * D4 + t];
            const float4 vrow = v4[(size_t)row * D4 + t];
            if (r <= 5) {                       // anchor k0, m = r-1
                acc[r]     = sq4(vk0, arow);
                acc[5 + r] = sq4(ak0, vrow);
            }
            acc[12 + (r - 2)] = sq4(vk1, arow); // anchor k1, m = r-2
            acc[17 + (r - 2)] = sq4(ak1, vrow);
        }
    } else {
        // generic path (k0 < SNUM: the reference's m==k duplicate breaks row
        // contiguity) — only 3 blocks; wave-uniform branch.
        #pragma unroll
        for (int m = 0; m < SNUM; ++m) {
            int t0 = k0 + m + 1; if (m == k0) t0 = k0 + 1; if (t0 >= B) t0 -= B;
            int t1 = k1 + m + 1; if (m == k1) t1 = k1 + 1; if (t1 >= B) t1 -= B;
            const float4 a0 = a4[(size_t)t0 * D4 + t];
            const float4 v0 = v4[(size_t)t0 * D4 + t];
            const float4 a1 = a4[(size_t)t1 * D4 + t];
            const float4 v1 = v4[(size_t)t1 * D4 + t];
            acc[1 + m]  = sq4(vk0, a0);
            acc[6 + m]  = sq4(ak0, v0);
            acc[12 + m] = sq4(vk1, a1);
            acc[17 + m] = sq4(ak1, v1);
        }
    }

    // 64-lane butterfly: each wave reduces its quarter of the row
    #pragma unroll
    for (int off = 32; off > 0; off >>= 1) {
        #pragma unroll
        for (int i = 0; i < 22; ++i)
            acc[i] += __shfl_xor(acc[i], off, 64);
    }

    // cross-wave combine in LDS BEFORE the nonlinear tail (R6's missing stage)
    __shared__ float sh[4][22];
    if (lane == 0) {
        #pragma unroll
        for (int i = 0; i < 22; ++i) sh[wave][i] = acc[i];
    }
    __syncthreads();

    if (t == 0) {
        float tot[22];
        #pragma unroll
        for (int i = 0; i < 22; ++i)
            tot[i] = sh[0][i] + sh[1][i] + sh[2][i] + sh[3][i];

        const float dp0 = sqrtf(tot[0]);
        float dn1_0 = sqrtf(tot[1]), dn2_0 = sqrtf(tot[6]);
        const float dp1 = sqrtf(tot[11]);
        float dn1_1 = sqrtf(tot[12]), dn2_1 = sqrtf(tot[17]);
        #pragma unroll
        for (int m = 1; m < SNUM; ++m) {
            dn1_0 = fminf(dn1_0, sqrtf(tot[1 + m]));
            dn2_0 = fminf(dn2_0, sqrtf(tot[6 + m]));
            dn1_1 = fminf(dn1_1, sqrtf(tot[12 + m]));
            dn2_1 = fminf(dn2_1, sqrtf(tot[17 + m]));
        }
        const float h0 = fmaxf(MARGINL + 2.0f * dp0 - dn1_0 - dn2_0, 0.0f);
        const float h1 = fmaxf(MARGINL + 2.0f * dp1 - dn1_1 - dn2_1, 0.0f);
        bsum[blockIdx.x] = h0 + h1;
    }
}

// Deterministic single-block mean: sum nblocks partials / B.
__global__ __launch_bounds__(1024) void mean_kernel(const float* __restrict__ bsum,
                                                    float* __restrict__ out,
                                                    int n, int B) {
    const int t = threadIdx.x;
    float s = 0.0f;
    for (int i = t; i < n; i += 1024) s += bsum[i];

    #pragma unroll
    for (int off = 32; off > 0; off >>= 1)
        s += __shfl_xor(s, off, 64);

    __shared__ float red[16];
    if ((t & 63) == 0) red[t >> 6] = s;
    __syncthreads();
    if (t == 0) {
        float tot = 0.0f;
        #pragma unroll
        for (int w = 0; w < 16; ++w) tot += red[w];
        out[0] = tot / (float)B;
    }
}

extern "C" void kernel_launch(void* const* d_in, const int* in_sizes, int n_in,
                              void* d_out, int out_size, void* d_ws, size_t ws_size,
                              hipStream_t stream) {
    const float* vfeat = (const float*)d_in[0];
    const float* afeat = (const float*)d_in[1];
    const int B = in_sizes[0] / DIM;
    const int nblocks = B / 2;

    float* bsum = (float*)d_ws;   // nblocks floats of scratch
    float* out  = (float*)d_out;

    hinge_kernel<<<nblocks, 256, 0, stream>>>(vfeat, afeat, bsum, B, nblocks);
    mean_kernel<<<1, 1024, 0, stream>>>(bsum, out, nblocks, B);
}

// Round 8
// 17.327 us; speedup vs baseline: 5.6266x; 1.3990x over previous
//
#include <hip/hip_runtime.h>
#include <math.h>

#define DIM 1024
#define D4  (DIM / 4)      // 256 float4 per row
#define SNUM 5
#define EPSL 1e-6f
#define MARGINL 1.0f

__device__ __forceinline__ float sq4(const float4& x, const float4& y) {
    float dx = x.x - y.x + EPSL;
    float dy = x.y - y.y + EPSL;
    float dz = x.z - y.z + EPSL;
    float dw = x.w - y.w + EPSL;
    return dx * dx + dy * dy + dz * dz + dw * dw;
}

// Merged-butterfly primitive: one shfl_xor step reduces across bit m AND merges
// two accumulators (lanes with bit m unset end up owning x's sum, set -> y's).
__device__ __forceinline__ float merge_red(float x, float y, int m, int lane) {
    const float send = (lane & m) ? x : y;
    const float recv = __shfl_xor(send, m, 64);
    const float keep = (lane & m) ? y : x;
    return keep + recv;
}

// One block (256 threads) per anchor k (R2 structure: max wave count, all 12
// row-loads per thread independent). The 11 partial sums are reduced with a
// MERGED butterfly: 14 cross-lane ops/wave instead of 66 — R2==R7 invariance
// showed the DS (shuffle) pipe, not fetch traffic, was the binding resource
// (1.08M shuffle ops in both = ~9us of DS-pipe serialization per CU).
__global__ __launch_bounds__(256) void hinge_kernel(const float* __restrict__ vfeat,
                                                    const float* __restrict__ afeat,
                                                    float* __restrict__ bsum,
                                                    int B, int nblocks) {
    // XCD-chunked bijective swizzle (R2: -46%): contiguous anchors per XCD.
    int b = blockIdx.x;
    if ((nblocks & 7) == 0) {
        const int chunk = nblocks >> 3;
        b = (b & 7) * chunk + (b >> 3);
    }
    const int k = b;
    const int t = threadIdx.x;
    const int wave = t >> 6;
    const int lane = t & 63;

    // wave-uniform negative indices
    int j[SNUM];
    #pragma unroll
    for (int m = 0; m < SNUM; ++m) {
        int tt = k + m + 1;
        if (m == k) tt = k + 1;          // reference's m==k case (only k<SNUM)
        if (tt >= B) tt -= B;
        j[m] = tt;
    }

    const float4* __restrict__ v4 = reinterpret_cast<const float4*>(vfeat);
    const float4* __restrict__ a4 = reinterpret_cast<const float4*>(afeat);

    const float4 vk = v4[(size_t)k * D4 + t];
    const float4 ak = a4[(size_t)k * D4 + t];

    // acc layout: [0]=pos, [1..5]=d_n1 partials, [6..10]=d_n2 partials, [11]=pad
    float acc[12];
    acc[0]  = sq4(vk, ak);
    acc[11] = 0.0f;
    #pragma unroll
    for (int m = 0; m < SNUM; ++m) {
        const float4 aj = a4[(size_t)j[m] * D4 + t];
        const float4 vj = v4[(size_t)j[m] * D4 + t];
        acc[1 + m] = sq4(vk, aj);
        acc[6 + m] = sq4(ak, vj);
    }

    // Merged butterfly: 14 shuffles reduce 12 accs across all 64 lanes.
    // After L1 (mask 32): content by bit5 (0=even acc, 1=odd).
    const float r0 = merge_red(acc[0],  acc[1],  32, lane);
    const float r1 = merge_red(acc[2],  acc[3],  32, lane);
    const float r2 = merge_red(acc[4],  acc[5],  32, lane);
    const float r3 = merge_red(acc[6],  acc[7],  32, lane);
    const float r4 = merge_red(acc[8],  acc[9],  32, lane);
    const float r5 = merge_red(acc[10], acc[11], 32, lane);
    // L2 (mask 16): content by bit4 (0=first arg).
    const float s0 = merge_red(r0, r1, 16, lane);   // accs 0-3:  id=2*b4+b5
    const float s1 = merge_red(r2, r3, 16, lane);   // accs 4-7
    const float s2 = merge_red(r4, r5, 16, lane);   // accs 8-11: id=8+2*b4+b5
    // L3 (mask 8): t0 by bit3; s2 self-reduces (id unchanged).
    const float t0 = merge_red(s0, s1, 8, lane);    // accs 0-7: id=4*b3+2*b4+b5
    const float t1 = s2 + __shfl_xor(s2, 8, 64);
    // L4 (mask 4): by bit2 (0 -> t0 accs 0-7, 1 -> t1 accs 8-11).
    float u = merge_red(t0, t1, 4, lane);
    // L5/L6: plain self-reduction (bits 1,0 carry no identity).
    u += __shfl_xor(u, 2, 64);
    u += __shfl_xor(u, 1, 64);

    // lane -> acc id, and one canonical representative lane per id
    const int b5 = (lane >> 5) & 1, b4 = (lane >> 4) & 1;
    const int b3 = (lane >> 3) & 1, b2 = (lane >> 2) & 1;
    const int id = b2 ? (8 + 2 * b4 + b5) : (4 * b3 + 2 * b4 + b5);
    const bool rep = ((lane & 3) == 0) && (!b2 || !b3);

    __shared__ float sh[4][12];
    if (rep) sh[wave][id] = u;
    __syncthreads();

    if (t == 0) {
        float tot[11];
        #pragma unroll
        for (int i = 0; i < 11; ++i)
            tot[i] = sh[0][i] + sh[1][i] + sh[2][i] + sh[3][i];

        const float d_p = sqrtf(tot[0]);
        float dn1 = sqrtf(tot[1]);
        float dn2 = sqrtf(tot[6]);
        #pragma unroll
        for (int m = 1; m < SNUM; ++m) {
            dn1 = fminf(dn1, sqrtf(tot[1 + m]));
            dn2 = fminf(dn2, sqrtf(tot[6 + m]));
        }
        bsum[blockIdx.x] = fmaxf(MARGINL + 2.0f * d_p - dn1 - dn2, 0.0f);
    }
}

// Deterministic single-block mean: sum n partials / B.
__global__ __launch_bounds__(1024) void mean_kernel(const float* __restrict__ bsum,
                                                    float* __restrict__ out,
                                                    int n, int B) {
    const int t = threadIdx.x;
    float s = 0.0f;
    for (int i = t; i < n; i += 1024) s += bsum[i];

    #pragma unroll
    for (int off = 32; off > 0; off >>= 1)
        s += __shfl_xor(s, off, 64);

    __shared__ float red[16];
    if ((t & 63) == 0) red[t >> 6] = s;
    __syncthreads();
    if (t == 0) {
        float tot = 0.0f;
        #pragma unroll
        for (int w = 0; w < 16; ++w) tot += red[w];
        out[0] = tot / (float)B;
    }
}

extern "C" void kernel_launch(void* const* d_in, const int* in_sizes, int n_in,
                              void* d_out, int out_size, void* d_ws, size_t ws_size,
                              hipStream_t stream) {
    const float* vfeat = (const float*)d_in[0];
    const float* afeat = (const float*)d_in[1];
    const int B = in_sizes[0] / DIM;
    const int nblocks = B;

    float* bsum = (float*)d_ws;   // B floats of scratch
    float* out  = (float*)d_out;

    hinge_kernel<<<nblocks, 256, 0, stream>>>(vfeat, afeat, bsum, B, nblocks);
    mean_kernel<<<1, 1024, 0, stream>>>(bsum, out, nblocks, B);
}

// Round 9
// 17.223 us; speedup vs baseline: 5.6606x; 1.0060x over previous
//
#include <hip/hip_runtime.h>
#include <math.h>

#define DIM 1024
#define D4  (DIM / 4)      // 256 float4 per row
#define SNUM 5
#define EPSL 1e-6f
#define MARGINL 1.0f

// (x + eps) - y per element, fma-accumulated: 2 VALU/element instead of 3
// (eps hoisted into the anchor row once per thread).
__device__ __forceinline__ float sqe4(const float4& xe, const float4& y) {
    const float dx = xe.x - y.x;
    const float dy = xe.y - y.y;
    const float dz = xe.z - y.z;
    const float dw = xe.w - y.w;
    float s = dx * dx;
    s = fmaf(dy, dy, s);
    s = fmaf(dz, dz, s);
    s = fmaf(dw, dw, s);
    return s;
}

// Merged-butterfly primitive: one shfl_xor step reduces across bit m AND merges
// two accumulators (lanes with bit m unset end up owning x's sum, set -> y's).
__device__ __forceinline__ float merge_red(float x, float y, int m, int lane) {
    const float send = (lane & m) ? x : y;
    const float recv = __shfl_xor(send, m, 64);
    const float keep = (lane & m) ? y : x;
    return keep + recv;
}

// One block (256 threads) per anchor k; thread t owns float4 slot t of each row.
// 12 independent row-loads up front (max MLP), 11 partials reduced with the
// merged butterfly (14 shuffles/wave, R8: -7us), eps hoisted into the anchor
// registers (2 VALU/element, this round's delta).
__global__ __launch_bounds__(256) void hinge_kernel(const float* __restrict__ vfeat,
                                                    const float* __restrict__ afeat,
                                                    float* __restrict__ bsum,
                                                    int B, int nblocks) {
    // XCD-chunked bijective swizzle (R2: -46%): contiguous anchors per XCD.
    int b = blockIdx.x;
    if ((nblocks & 7) == 0) {
        const int chunk = nblocks >> 3;
        b = (b & 7) * chunk + (b >> 3);
    }
    const int k = b;
    const int t = threadIdx.x;
    const int wave = t >> 6;
    const int lane = t & 63;

    // wave-uniform negative indices
    int j[SNUM];
    #pragma unroll
    for (int m = 0; m < SNUM; ++m) {
        int tt = k + m + 1;
        if (m == k) tt = k + 1;          // reference's m==k case (only k<SNUM)
        if (tt >= B) tt -= B;
        j[m] = tt;
    }

    const float4* __restrict__ v4 = reinterpret_cast<const float4*>(vfeat);
    const float4* __restrict__ a4 = reinterpret_cast<const float4*>(afeat);

    const float4 vk = v4[(size_t)k * D4 + t];
    const float4 ak = a4[(size_t)k * D4 + t];
    const float4 vke = make_float4(vk.x + EPSL, vk.y + EPSL, vk.z + EPSL, vk.w + EPSL);
    const float4 ake = make_float4(ak.x + EPSL, ak.y + EPSL, ak.z + EPSL, ak.w + EPSL);

    // acc layout: [0]=pos, [1..5]=d_n1 partials, [6..10]=d_n2 partials, [11]=pad
    float acc[12];
    acc[0]  = sqe4(vke, ak);
    acc[11] = 0.0f;
    #pragma unroll
    for (int m = 0; m < SNUM; ++m) {
        const float4 aj = a4[(size_t)j[m] * D4 + t];
        const float4 vj = v4[(size_t)j[m] * D4 + t];
        acc[1 + m] = sqe4(vke, aj);   // ||v_k - a_j + eps||^2 partial
        acc[6 + m] = sqe4(ake, vj);   // ||a_k - v_j + eps||^2 partial
    }

    // Merged butterfly: 14 shuffles reduce 12 accs across all 64 lanes.
    const float r0 = merge_red(acc[0],  acc[1],  32, lane);
    const float r1 = merge_red(acc[2],  acc[3],  32, lane);
    const float r2 = merge_red(acc[4],  acc[5],  32, lane);
    const float r3 = merge_red(acc[6],  acc[7],  32, lane);
    const float r4 = merge_red(acc[8],  acc[9],  32, lane);
    const float r5 = merge_red(acc[10], acc[11], 32, lane);
    const float s0 = merge_red(r0, r1, 16, lane);   // accs 0-3:  id=2*b4+b5
    const float s1 = merge_red(r2, r3, 16, lane);   // accs 4-7
    const float s2 = merge_red(r4, r5, 16, lane);   // accs 8-11: id=8+2*b4+b5
    const float t0 = merge_red(s0, s1, 8, lane);    // accs 0-7: id=4*b3+2*b4+b5
    const float t1 = s2 + __shfl_xor(s2, 8, 64);
    float u = merge_red(t0, t1, 4, lane);
    u += __shfl_xor(u, 2, 64);
    u += __shfl_xor(u, 1, 64);

    // lane -> acc id, one canonical representative lane per id
    const int b5 = (lane >> 5) & 1, b4 = (lane >> 4) & 1;
    const int b3 = (lane >> 3) & 1, b2 = (lane >> 2) & 1;
    const int id = b2 ? (8 + 2 * b4 + b5) : (4 * b3 + 2 * b4 + b5);
    const bool rep = ((lane & 3) == 0) && (!b2 || !b3);

    __shared__ float sh[4][12];
    if (rep) sh[wave][id] = u;
    __syncthreads();

    if (t == 0) {
        float tot[11];
        #pragma unroll
        for (int i = 0; i < 11; ++i)
            tot[i] = sh[0][i] + sh[1][i] + sh[2][i] + sh[3][i];

        const float d_p = sqrtf(tot[0]);
        float dn1 = sqrtf(tot[1]);
        float dn2 = sqrtf(tot[6]);
        #pragma unroll
        for (int m = 1; m < SNUM; ++m) {
            dn1 = fminf(dn1, sqrtf(tot[1 + m]));
            dn2 = fminf(dn2, sqrtf(tot[6 + m]));
        }
        bsum[blockIdx.x] = fmaxf(MARGINL + 2.0f * d_p - dn1 - dn2, 0.0f);
    }
}

// Deterministic single-block mean: sum n partials / B.
__global__ __launch_bounds__(1024) void mean_kernel(const float* __restrict__ bsum,
                                                    float* __restrict__ out,
                                                    int n, int B) {
    const int t = threadIdx.x;
    float s = 0.0f;
    for (int i = t; i < n; i += 1024) s += bsum[i];

    #pragma unroll
    for (int off = 32; off > 0; off >>= 1)
        s += __shfl_xor(s, off, 64);

    __shared__ float red[16];
    if ((t & 63) == 0) red[t >> 6] = s;
    __syncthreads();
    if (t == 0) {
        float tot = 0.0f;
        #pragma unroll
        for (int w = 0; w < 16; ++w) tot += red[w];
        out[0] = tot / (float)B;
    }
}

extern "C" void kernel_launch(void* const* d_in, const int* in_sizes, int n_in,
                              void* d_out, int out_size, void* d_ws, size_t ws_size,
                              hipStream_t stream) {
    const float* vfeat = (const float*)d_in[0];
    const float* afeat = (const float*)d_in[1];
    const int B = in_sizes[0] / DIM;
    const int nblocks = B;

    float* bsum = (float*)d_ws;   // B floats of scratch
    float* out  = (float*)d_out;

    hinge_kernel<<<nblocks, 256, 0, stream>>>(vfeat, afeat, bsum, B, nblocks);
    mean_kernel<<<1, 1024, 0, stream>>>(bsum, out, nblocks, B);
}